// Round 1
// baseline (2751.306 us; speedup 1.0000x reference)
//
#include <hip/hip_runtime.h>
#include <math.h>

#define NN 50000
#define NE 800000

// ---- float <-> monotone unsigned key (for atomicMax on floats) ----
__device__ __forceinline__ unsigned fkey(float f) {
  unsigned u = __float_as_uint(f);
  return (u & 0x80000000u) ? ~u : (u | 0x80000000u);
}
__device__ __forceinline__ float fkey_dec(unsigned k) {
  return (k & 0x80000000u) ? __uint_as_float(k ^ 0x80000000u)
                           : __uint_as_float(~k);
}

// K1: accumulate sum over edges of radial[e,c,f]^2 into norm_acc[16]
__global__ __launch_bounds__(256)
void k_radnorm(const float* __restrict__ coord, const int* __restrict__ row,
               const int* __restrict__ col, float* __restrict__ norm_acc) {
  const int lane = threadIdx.x & 63;
  const int cf = lane & 15;        // which (c,f) pair
  const int eg = lane >> 4;        // which of 4 edges in the group
  const int c4 = cf >> 2, f4 = cf & 3;
  const int wid = blockIdx.x * (blockDim.x >> 6) + (threadIdx.x >> 6);
  const int nw = gridDim.x * (blockDim.x >> 6);
  float acc = 0.f;
  for (int base = wid * 4; base < NE; base += nw * 4) {
    int e = base + eg;             // safe: NE % 4 == 0
    int r = row[e], c = col[e];
    const float* cr = coord + r * 12;
    const float* cc = coord + c * 12;
    float rad = 0.f;
#pragma unroll
    for (int d = 0; d < 3; ++d) {
      float a = cr[c4 * 3 + d] - cc[c4 * 3 + d];
      float b = cr[f4 * 3 + d] - cc[f4 * 3 + d];
      rad += a * b;
    }
    acc += rad * rad;
  }
  acc += __shfl_xor(acc, 16);
  acc += __shfl_xor(acc, 32);
  if (lane < 16) atomicAdd(norm_acc + cf, acc);
}

// K2: rnorm = 1 / max(sqrt(acc), EPS)
__global__ void k_norm_fin(const float* __restrict__ norm_acc,
                           float* __restrict__ rnorm) {
  int i = threadIdx.x;
  if (i < 16) {
    float n = fmaxf(sqrtf(norm_acc[i]), 1e-12f);
    rnorm[i] = 1.0f / n;
  }
}

// K3: per edge -> alpha = q.k ; atomic seg_max
__global__ __launch_bounds__(256)
void k_alpha(const float* __restrict__ h, const float* __restrict__ coord,
             const int* __restrict__ row, const int* __restrict__ col,
             const float* __restrict__ edge_attr,
             const float* __restrict__ Wq, const float* __restrict__ bq,
             const float* __restrict__ Wkv, const float* __restrict__ bkv,
             const float* __restrict__ rnorm,
             float* __restrict__ alpha_out, unsigned* __restrict__ seg_max) {
  __shared__ float sWq[64 * 64];     // Wq[i][j]
  __shared__ float sWk[96 * 64];     // Wkv[i][2j]  (k columns)
  __shared__ float sFeat[4][96];
  __shared__ float sHr[4][64];

  const int tid = threadIdx.x;
  for (int idx = tid; idx < 64 * 64; idx += 256) sWq[idx] = Wq[idx];
  for (int idx = tid; idx < 96 * 64; idx += 256) {
    int i = idx >> 6, j = idx & 63;
    sWk[idx] = Wkv[i * 128 + 2 * j];
  }
  __syncthreads();

  const int lane = tid & 63;
  const int wvid = tid >> 6;
  const int wave_global = blockIdx.x * 4 + wvid;
  const int n_waves = gridDim.x * 4;
  float* feat = sFeat[wvid];
  float* hr = sHr[wvid];

  const float bqv = bq[lane];
  const float bkE = bkv[2 * lane];
  const float rn = (lane < 16) ? rnorm[lane] : 0.f;
  const int c4 = (lane & 15) >> 2, f4 = lane & 3;

  for (int e = wave_global; e < NE; e += n_waves) {
    const int r = row[e], c = col[e];
    float cd = 0.f;
    if (lane < 12) cd = coord[r * 12 + lane] - coord[c * 12 + lane];
    float rad = 0.f;
#pragma unroll
    for (int d = 0; d < 3; ++d)
      rad += __shfl(cd, c4 * 3 + d) * __shfl(cd, f4 * 3 + d);
    if (lane < 16) {
      feat[lane] = rad * rn;
      feat[80 + lane] = edge_attr[e * 16 + lane];
    }
    hr[lane] = h[r * 64 + lane];
    feat[16 + lane] = h[c * 64 + lane];

    float q = bqv;
#pragma unroll 8
    for (int i = 0; i < 64; ++i) q += hr[i] * sWq[i * 64 + lane];
    float k = bkE;
#pragma unroll 8
    for (int i = 0; i < 96; ++i) k += feat[i] * sWk[i * 64 + lane];

    float p = q * k;
#pragma unroll
    for (int off = 32; off; off >>= 1) p += __shfl_xor(p, off);
    if (lane == 0) {
      alpha_out[e] = p;
      atomicMax(seg_max + r, fkey(p));
    }
  }
}

// K5: per edge -> v, ex, accumulate seg_sum / h_acc / coord_acc (unnormalized)
__global__ __launch_bounds__(256)
void k_vpass(const float* __restrict__ h, const float* __restrict__ coord,
             const int* __restrict__ row, const int* __restrict__ col,
             const float* __restrict__ edge_attr,
             const float* __restrict__ Wkv, const float* __restrict__ bkv,
             const float* __restrict__ W1, const float* __restrict__ b1,
             const float* __restrict__ W2, const float* __restrict__ rnorm,
             const float* __restrict__ alpha, const unsigned* __restrict__ seg_max,
             float* __restrict__ seg_sum, float* __restrict__ h_acc,
             float* __restrict__ coord_acc, float* __restrict__ ex_out) {
  __shared__ float sWv[96 * 64];     // Wkv[i][2j+1]  (v columns)
  __shared__ float sW1[64 * 64];
  __shared__ float sFeat[4][96];
  __shared__ float sV[4][64];

  const int tid = threadIdx.x;
  for (int idx = tid; idx < 96 * 64; idx += 256) {
    int i = idx >> 6, j = idx & 63;
    sWv[idx] = Wkv[i * 128 + 2 * j + 1];
  }
  for (int idx = tid; idx < 64 * 64; idx += 256) sW1[idx] = W1[idx];
  __syncthreads();

  const int lane = tid & 63;
  const int wvid = tid >> 6;
  const int wave_global = blockIdx.x * 4 + wvid;
  const int n_waves = gridDim.x * 4;
  float* feat = sFeat[wvid];
  float* vv = sV[wvid];

  const float bvO = bkv[2 * lane + 1];
  const float b1v = b1[lane];
  const float4 w2r = ((const float4*)W2)[lane];   // W2[lane][0..3]
  const float rn = (lane < 16) ? rnorm[lane] : 0.f;
  const int c4 = (lane & 15) >> 2, f4 = lane & 3;

  for (int e = wave_global; e < NE; e += n_waves) {
    const int r = row[e], c = col[e];
    float cd = 0.f;
    if (lane < 12) cd = coord[r * 12 + lane] - coord[c * 12 + lane];
    float rad = 0.f;
#pragma unroll
    for (int d = 0; d < 3; ++d)
      rad += __shfl(cd, c4 * 3 + d) * __shfl(cd, f4 * 3 + d);
    if (lane < 16) {
      feat[lane] = rad * rn;
      feat[80 + lane] = edge_attr[e * 16 + lane];
    }
    feat[16 + lane] = h[c * 64 + lane];

    float v = bvO;
#pragma unroll 8
    for (int i = 0; i < 96; ++i) v += feat[i] * sWv[i * 64 + lane];

    const float mx = fkey_dec(seg_max[r]);
    const float ex = __expf(alpha[e] - mx);
    if (lane == 0) {
      ex_out[e] = ex;
      atomicAdd(seg_sum + r, ex);
    }
    atomicAdd(h_acc + r * 64 + lane, ex * v);

    vv[lane] = v;
    float t = b1v;
#pragma unroll 8
    for (int i = 0; i < 64; ++i) t += vv[i] * sW1[i * 64 + lane];
    t = t / (1.f + __expf(-t));          // silu

    float p0 = t * w2r.x, p1 = t * w2r.y, p2 = t * w2r.z, p3 = t * w2r.w;
#pragma unroll
    for (int off = 32; off; off >>= 1) {
      p0 += __shfl_xor(p0, off);
      p1 += __shfl_xor(p1, off);
      p2 += __shfl_xor(p2, off);
      p3 += __shfl_xor(p3, off);
    }
    if (lane < 12) {
      int ci = lane / 3;
      float cvv = (ci == 0) ? p0 : (ci == 1) ? p1 : (ci == 2) ? p2 : p3;
      atomicAdd(coord_acc + r * 12 + lane, cd * cvv * ex);
    }
  }
}

// K6: finalize h_out, coord_out, att
__global__ __launch_bounds__(256)
void k_finalize(const float* __restrict__ h, const float* __restrict__ coord,
                const int* __restrict__ row, const float* __restrict__ seg_sum,
                const float* __restrict__ h_acc, const float* __restrict__ coord_acc,
                const float* __restrict__ ex, float* __restrict__ out) {
  const int H_SZ = NN * 64;
  const int C_SZ = NN * 12;
  int gid = blockIdx.x * 256 + threadIdx.x;
  if (gid < H_SZ) {
    int n = gid >> 6;
    float s = seg_sum[n];
    float add = (s > 0.f) ? h_acc[gid] / s : 0.f;
    out[gid] = h[gid] + add;
  } else if (gid < H_SZ + C_SZ) {
    int i = gid - H_SZ;
    int n = i / 12;
    float s = seg_sum[n];
    float add = (s > 0.f) ? coord_acc[i] / s : 0.f;
    out[gid] = coord[i] + add;
  } else if (gid < H_SZ + C_SZ + NE) {
    int e = gid - H_SZ - C_SZ;
    out[gid] = ex[e] / seg_sum[row[e]];
  }
}

extern "C" void kernel_launch(void* const* d_in, const int* in_sizes, int n_in,
                              void* d_out, int out_size, void* d_ws, size_t ws_size,
                              hipStream_t stream) {
  const float* h        = (const float*)d_in[0];
  const float* coord    = (const float*)d_in[1];
  const int*   row      = (const int*)d_in[2];
  const int*   col      = (const int*)d_in[3];
  const float* edge_attr= (const float*)d_in[4];
  const float* Wq       = (const float*)d_in[5];
  const float* bq       = (const float*)d_in[6];
  const float* Wkv      = (const float*)d_in[7];
  const float* bkv      = (const float*)d_in[8];
  const float* W1       = (const float*)d_in[9];
  const float* b1       = (const float*)d_in[10];
  const float* W2       = (const float*)d_in[11];
  float* out = (float*)d_out;
  float* ws  = (float*)d_ws;

  // ws layout (floats):
  // [0..16)                norm_acc           (zeroed)
  // [16..16+NN)            seg_max (as u32)   (zeroed -> below any fkey)
  // [16+NN..16+2NN)        seg_sum            (zeroed)
  // [16+2NN..16+66NN)      h_acc              (zeroed)
  // [16+66NN..16+78NN)     coord_acc          (zeroed)
  // [zend..zend+NE)        alpha
  // [zend+NE..zend+2NE)    ex
  // [zend+2NE..+16)        rnorm
  float*    norm_acc  = ws;
  unsigned* seg_max   = (unsigned*)(ws + 16);
  float*    seg_sum   = ws + 16 + NN;
  float*    h_acc     = ws + 16 + 2 * (size_t)NN;
  float*    coord_acc = ws + 16 + 66 * (size_t)NN;
  const size_t zend   = 16 + 78 * (size_t)NN;
  float*    alpha     = ws + zend;
  float*    exbuf     = ws + zend + NE;
  float*    rnorm     = ws + zend + 2 * (size_t)NE;

  hipMemsetAsync(d_ws, 0, zend * sizeof(float), stream);

  k_radnorm<<<512, 256, 0, stream>>>(coord, row, col, norm_acc);
  k_norm_fin<<<1, 64, 0, stream>>>(norm_acc, rnorm);
  k_alpha<<<1024, 256, 0, stream>>>(h, coord, row, col, edge_attr, Wq, bq, Wkv,
                                    bkv, rnorm, alpha, seg_max);
  k_vpass<<<1024, 256, 0, stream>>>(h, coord, row, col, edge_attr, Wkv, bkv, W1,
                                    b1, W2, rnorm, alpha, seg_max, seg_sum,
                                    h_acc, coord_acc, exbuf);
  const int total = NN * 64 + NN * 12 + NE;
  k_finalize<<<(total + 255) / 256, 256, 0, stream>>>(h, coord, row, seg_sum,
                                                      h_acc, coord_acc, exbuf, out);
}

// Round 2
// 1343.813 us; speedup vs baseline: 2.0474x; 2.0474x over previous
//
#include <hip/hip_runtime.h>
#include <math.h>

#define NN 50000
#define NE 800000

// ---- bf16 pack/unpack (RTN) ----
__device__ __forceinline__ unsigned pack_bf(float a, float b) {
  unsigned ua = __float_as_uint(a); ua += 0x7fffu + ((ua >> 16) & 1u);
  unsigned ub = __float_as_uint(b); ub += 0x7fffu + ((ub >> 16) & 1u);
  return (ua >> 16) | (ub & 0xffff0000u);
}
__device__ __forceinline__ float blo(unsigned w) { return __uint_as_float(w << 16); }
__device__ __forceinline__ float bhi(unsigned w) { return __uint_as_float(w & 0xffff0000u); }

// K1: accumulate sum over edges of radial[e,c,f]^2 into norm_acc[16]
__global__ __launch_bounds__(256)
void k_radnorm(const float* __restrict__ coord, const int* __restrict__ row,
               const int* __restrict__ col, float* __restrict__ norm_acc) {
  const int lane = threadIdx.x & 63;
  const int cf = lane & 15;
  const int eg = lane >> 4;
  const int c4 = cf >> 2, f4 = cf & 3;
  const int wid = blockIdx.x * (blockDim.x >> 6) + (threadIdx.x >> 6);
  const int nw = gridDim.x * (blockDim.x >> 6);
  float acc = 0.f;
  for (int base = wid * 4; base < NE; base += nw * 4) {
    int e = base + eg;
    int r = row[e], c = col[e];
    const float* cr = coord + r * 12;
    const float* cc = coord + c * 12;
    float rad = 0.f;
#pragma unroll
    for (int d = 0; d < 3; ++d) {
      float a = cr[c4 * 3 + d] - cc[c4 * 3 + d];
      float b = cr[f4 * 3 + d] - cc[f4 * 3 + d];
      rad += a * b;
    }
    acc += rad * rad;
  }
  acc += __shfl_xor(acc, 16);
  acc += __shfl_xor(acc, 32);
  if (lane < 16) atomicAdd(norm_acc + cf, acc);
}

__global__ void k_norm_fin(const float* __restrict__ norm_acc,
                           float* __restrict__ rnorm) {
  int i = threadIdx.x;
  if (i < 16) rnorm[i] = 1.0f / fmaxf(sqrtf(norm_acc[i]), 1e-12f);
}

// CSR build
__global__ void k_count(const int* __restrict__ row, int* __restrict__ deg) {
  int e = blockIdx.x * 256 + threadIdx.x;
  if (e < NE) atomicAdd(deg + row[e], 1);
}

__global__ void k_scan(const int* __restrict__ deg, int* __restrict__ startA,
                       int* __restrict__ cursor) {
  __shared__ int part[1024];
  const int t = threadIdx.x;
  const int CH = (NN + 1023) / 1024;
  const int lo = t * CH, hi = (lo + CH < NN) ? lo + CH : NN;
  int s = 0;
  for (int i = lo; i < hi; ++i) s += deg[i];
  part[t] = s;
  __syncthreads();
  for (int off = 1; off < 1024; off <<= 1) {
    int v = (t >= off) ? part[t - off] : 0;
    __syncthreads();
    part[t] += v;
    __syncthreads();
  }
  int base = (t == 0) ? 0 : part[t - 1];
  for (int i = lo; i < hi; ++i) {
    startA[i] = base; cursor[i] = base; base += deg[i];
  }
  if (t == 1023) startA[NN] = base;
}

__global__ void k_scatter(const int* __restrict__ row, int* __restrict__ cursor,
                          int* __restrict__ eperm) {
  int e = blockIdx.x * 256 + threadIdx.x;
  if (e < NE) {
    int p = atomicAdd(cursor + row[e], 1);
    eperm[p] = e;
  }
}

// Main: one wave per node; 4-edge chunks; fused online softmax; no atomics.
__global__ __launch_bounds__(256, 3)
void k_main(const float* __restrict__ h, const float* __restrict__ coord,
            const int* __restrict__ col, const float* __restrict__ edge_attr,
            const float* __restrict__ Wq, const float* __restrict__ bq,
            const float* __restrict__ Wkv, const float* __restrict__ bkv,
            const float* __restrict__ W1, const float* __restrict__ b1,
            const float* __restrict__ W2, const float* __restrict__ rnorm,
            const int* __restrict__ startA, const int* __restrict__ eperm,
            float* __restrict__ walpha, float* __restrict__ out) {
  __shared__ uint2 sKV[48 * 64];      // (k,v) bf16 pairs, 2 k-steps per uint2
  __shared__ unsigned sW1p[32 * 64];  // W1 bf16 pairs (2 k-steps)
  __shared__ unsigned sWqp[32 * 64];  // Wq bf16 pairs (2 k-steps)
  __shared__ float sFeat[4][4][96];
  __shared__ float sV[4][4][64];
  __shared__ float sHr[4][64];

  const int tid = threadIdx.x;
  for (int idx = tid; idx < 48 * 64; idx += 256) {
    int i2 = idx >> 6, j = idx & 63;
    const float* wp0 = Wkv + (2 * i2) * 128 + 2 * j;
    const float* wp1 = Wkv + (2 * i2 + 1) * 128 + 2 * j;
    sKV[idx] = make_uint2(pack_bf(wp0[0], wp0[1]), pack_bf(wp1[0], wp1[1]));
  }
  for (int idx = tid; idx < 32 * 64; idx += 256) {
    int i2 = idx >> 6, j = idx & 63;
    sW1p[idx] = pack_bf(W1[(2 * i2) * 64 + j], W1[(2 * i2 + 1) * 64 + j]);
    sWqp[idx] = pack_bf(Wq[(2 * i2) * 64 + j], Wq[(2 * i2 + 1) * 64 + j]);
  }
  __syncthreads();

  const int wv = tid >> 6, lane = tid & 63;
  const int node = blockIdx.x * 4 + wv;   // grid = NN/4 exactly
  const int grp = lane >> 4, g = lane & 15;
  const int c4 = g >> 2, f4 = g & 3;
  const int ci = (g < 12) ? (g / 3) : 0;
  const int cvidx = grp * 4 + ci;
  const float rn = rnorm[g];
  const float bk = bkv[2 * lane], bv = bkv[2 * lane + 1];
  const float b1v = b1[lane];
  const float4 w2r = ((const float4*)W2)[lane];

  // q = h[node] @ Wq + bq
  sHr[wv][lane] = h[node * 64 + lane];
  float q = bq[lane];
  {
    const float2* hp = (const float2*)sHr[wv];
#pragma unroll 8
    for (int i2 = 0; i2 < 32; ++i2) {
      unsigned w = sWqp[i2 * 64 + lane];
      float2 hb = hp[i2];
      q += hb.x * blo(w) + hb.y * bhi(w);
    }
  }

  const int s0 = startA[node], s1 = startA[node + 1];
  float m = -INFINITY, l = 0.f, hacc = 0.f, cacc = 0.f;

  float* fgrp = sFeat[wv][grp];
  const float2* pf0 = (const float2*)sFeat[wv][0];
  const float2* pf1 = (const float2*)sFeat[wv][1];
  const float2* pf2 = (const float2*)sFeat[wv][2];
  const float2* pf3 = (const float2*)sFeat[wv][3];
  const float2* pv0 = (const float2*)sV[wv][0];
  const float2* pv1 = (const float2*)sV[wv][1];
  const float2* pv2 = (const float2*)sV[wv][2];
  const float2* pv3 = (const float2*)sV[wv][3];

  for (int j = s0; j < s1; j += 4) {
    const int nval = s1 - j;
    const int js = j + (grp < nval ? grp : nval - 1);
    const int e = eperm[js];
    const int cnode = col[e];
    float cd = 0.f;
    if (g < 12) cd = coord[node * 12 + g] - coord[cnode * 12 + g];
    float rad = 0.f;
#pragma unroll
    for (int d = 0; d < 3; ++d)
      rad += __shfl(cd, grp * 16 + c4 * 3 + d) * __shfl(cd, grp * 16 + f4 * 3 + d);
    fgrp[g] = rad * rn;
    fgrp[80 + g] = edge_attr[e * 16 + g];
#pragma unroll
    for (int s = 0; s < 4; ++s) {
      int cs = __shfl(cnode, s * 16);
      sFeat[wv][s][16 + lane] = h[cs * 64 + lane];
    }

    // k, v for 4 edges (lane = output column)
    float k0 = bk, k1 = bk, k2 = bk, k3 = bk;
    float v0 = bv, v1 = bv, v2 = bv, v3 = bv;
#pragma unroll 4
    for (int i2 = 0; i2 < 48; ++i2) {
      uint2 w = sKV[i2 * 64 + lane];
      float wk0 = blo(w.x), wv0_ = bhi(w.x), wk1 = blo(w.y), wv1_ = bhi(w.y);
      float2 fa = pf0[i2], fb = pf1[i2], fc = pf2[i2], fd = pf3[i2];
      k0 += fa.x * wk0 + fa.y * wk1;  v0 += fa.x * wv0_ + fa.y * wv1_;
      k1 += fb.x * wk0 + fb.y * wk1;  v1 += fb.x * wv0_ + fb.y * wv1_;
      k2 += fc.x * wk0 + fc.y * wk1;  v2 += fc.x * wv0_ + fc.y * wv1_;
      k3 += fd.x * wk0 + fd.y * wk1;  v3 += fd.x * wv0_ + fd.y * wv1_;
    }

    // alpha (wave all-reduce ×4)
    float a0 = q * k0, a1 = q * k1, a2 = q * k2, a3 = q * k3;
#pragma unroll
    for (int off = 1; off < 64; off <<= 1) {
      a0 += __shfl_xor(a0, off);
      a1 += __shfl_xor(a1, off);
      a2 += __shfl_xor(a2, off);
      a3 += __shfl_xor(a3, off);
    }
    if (nval <= 1) a1 = -INFINITY;
    if (nval <= 2) a2 = -INFINITY;
    if (nval <= 3) a3 = -INFINITY;

    float m_new = fmaxf(fmaxf(fmaxf(a0, a1), fmaxf(a2, a3)), m);
    float scale = __expf(m - m_new);   // first chunk: exp(-inf)=0
    float e0 = __expf(a0 - m_new), e1 = __expf(a1 - m_new);
    float e2 = __expf(a2 - m_new), e3 = __expf(a3 - m_new);
    l = l * scale + e0 + e1 + e2 + e3;
    hacc = hacc * scale + e0 * v0 + e1 * v1 + e2 * v2 + e3 * v3;
    m = m_new;
    if (g == 0 && grp < nval) {
      float asel = (grp == 0) ? a0 : (grp == 1) ? a1 : (grp == 2) ? a2 : a3;
      walpha[j + grp] = asel;
    }

    // t = silu(v @ W1 + b1)
    sV[wv][0][lane] = v0; sV[wv][1][lane] = v1;
    sV[wv][2][lane] = v2; sV[wv][3][lane] = v3;
    float t0 = b1v, t1 = b1v, t2 = b1v, t3 = b1v;
#pragma unroll 4
    for (int i2 = 0; i2 < 32; ++i2) {
      unsigned w = sW1p[i2 * 64 + lane];
      float wl = blo(w), wh = bhi(w);
      float2 va = pv0[i2], vb = pv1[i2], vc = pv2[i2], vd = pv3[i2];
      t0 += va.x * wl + va.y * wh;
      t1 += vb.x * wl + vb.y * wh;
      t2 += vc.x * wl + vc.y * wh;
      t3 += vd.x * wl + vd.y * wh;
    }
    t0 = t0 / (1.f + __expf(-t0)); t1 = t1 / (1.f + __expf(-t1));
    t2 = t2 / (1.f + __expf(-t2)); t3 = t3 / (1.f + __expf(-t3));

    // cv[s][c] = sum_j t_s[j] * W2[j][c]  (16 wave all-reduces)
    float cvt[16];
    cvt[0] = t0 * w2r.x; cvt[1] = t0 * w2r.y; cvt[2] = t0 * w2r.z; cvt[3] = t0 * w2r.w;
    cvt[4] = t1 * w2r.x; cvt[5] = t1 * w2r.y; cvt[6] = t1 * w2r.z; cvt[7] = t1 * w2r.w;
    cvt[8] = t2 * w2r.x; cvt[9] = t2 * w2r.y; cvt[10] = t2 * w2r.z; cvt[11] = t2 * w2r.w;
    cvt[12] = t3 * w2r.x; cvt[13] = t3 * w2r.y; cvt[14] = t3 * w2r.z; cvt[15] = t3 * w2r.w;
#pragma unroll
    for (int off = 1; off < 64; off <<= 1) {
#pragma unroll
      for (int t = 0; t < 16; ++t) cvt[t] += __shfl_xor(cvt[t], off);
    }
    float cvv = cvt[0];
#pragma unroll
    for (int t = 1; t < 16; ++t) cvv = (cvidx == t) ? cvt[t] : cvv;
    float eg_ = (grp == 0) ? e0 : (grp == 1) ? e1 : (grp == 2) ? e2 : e3;
    cacc = cacc * scale + eg_ * cvv * cd;   // cd==0 for g>=12; eg_==0 for padded slots
  }

  const float inv = (l > 0.f) ? 1.f / l : 0.f;
  out[node * 64 + lane] = h[node * 64 + lane] + hacc * inv;
  cacc += __shfl_xor(cacc, 16);
  cacc += __shfl_xor(cacc, 32);
  if (lane < 12)
    out[NN * 64 + node * 12 + lane] = coord[node * 12 + lane] + cacc * inv;
  for (int j2 = s0 + lane; j2 < s1; j2 += 64)
    out[NN * 64 + NN * 12 + eperm[j2]] = __expf(walpha[j2] - m) * inv;
}

extern "C" void kernel_launch(void* const* d_in, const int* in_sizes, int n_in,
                              void* d_out, int out_size, void* d_ws, size_t ws_size,
                              hipStream_t stream) {
  const float* h         = (const float*)d_in[0];
  const float* coord     = (const float*)d_in[1];
  const int*   row       = (const int*)d_in[2];
  const int*   col       = (const int*)d_in[3];
  const float* edge_attr = (const float*)d_in[4];
  const float* Wq        = (const float*)d_in[5];
  const float* bq        = (const float*)d_in[6];
  const float* Wkv       = (const float*)d_in[7];
  const float* bkv       = (const float*)d_in[8];
  const float* W1        = (const float*)d_in[9];
  const float* b1        = (const float*)d_in[10];
  const float* W2        = (const float*)d_in[11];
  float* out = (float*)d_out;
  float* f   = (float*)d_ws;

  float* norm_acc = f;                              // 16 (zeroed)
  int*   deg      = (int*)(f + 16);                 // NN (zeroed)
  int*   startA   = (int*)(f + 16 + NN);            // NN+1
  int*   cursor   = (int*)(f + 16 + 2 * NN + 1);    // NN
  int*   eperm    = (int*)(f + 16 + 3 * NN + 1);    // NE
  float* walpha   = f + 16 + 3 * (size_t)NN + 1 + NE;        // NE
  float* rnorm    = f + 16 + 3 * (size_t)NN + 1 + 2 * (size_t)NE; // 16

  hipMemsetAsync(d_ws, 0, (16 + NN) * sizeof(float), stream);

  k_radnorm<<<512, 256, 0, stream>>>(coord, row, col, norm_acc);
  k_norm_fin<<<1, 64, 0, stream>>>(norm_acc, rnorm);
  k_count<<<(NE + 255) / 256, 256, 0, stream>>>(row, deg);
  k_scan<<<1, 1024, 0, stream>>>(deg, startA, cursor);
  k_scatter<<<(NE + 255) / 256, 256, 0, stream>>>(row, cursor, eperm);
  k_main<<<NN / 4, 256, 0, stream>>>(h, coord, col, edge_attr, Wq, bq, Wkv, bkv,
                                     W1, b1, W2, rnorm, startA, eperm, walpha, out);
}

// Round 3
// 945.666 us; speedup vs baseline: 2.9094x; 1.4210x over previous
//
#include <hip/hip_runtime.h>
#include <math.h>

#define NN 50000
#define NE 800000

typedef __attribute__((ext_vector_type(8))) short short8;
typedef __attribute__((ext_vector_type(4))) float floatx4;

__device__ __forceinline__ unsigned short bf16_of(float x) {
  unsigned u = __float_as_uint(x);
  u += 0x7fffu + ((u >> 16) & 1u);
  return (unsigned short)(u >> 16);
}
__device__ __forceinline__ float bf2f(unsigned short u) {
  return __uint_as_float(((unsigned)u) << 16);
}
__device__ __forceinline__ unsigned pack_bf(float a, float b) {
  unsigned ua = __float_as_uint(a); ua += 0x7fffu + ((ua >> 16) & 1u);
  unsigned ub = __float_as_uint(b); ub += 0x7fffu + ((ub >> 16) & 1u);
  return (ua >> 16) | (ub & 0xffff0000u);
}
__device__ __forceinline__ float blo(unsigned w) { return __uint_as_float(w << 16); }
__device__ __forceinline__ float bhi(unsigned w) { return __uint_as_float(w & 0xffff0000u); }

// ---------------- norm over all edges ----------------
__global__ __launch_bounds__(256)
void k_radnorm(const float* __restrict__ coord, const int* __restrict__ row,
               const int* __restrict__ col, float* __restrict__ norm_acc) {
  const int lane = threadIdx.x & 63;
  const int cf = lane & 15;
  const int eg = lane >> 4;
  const int c4 = cf >> 2, f4 = cf & 3;
  const int wid = blockIdx.x * (blockDim.x >> 6) + (threadIdx.x >> 6);
  const int nw = gridDim.x * (blockDim.x >> 6);
  float acc = 0.f;
  for (int base = wid * 4; base < NE; base += nw * 4) {
    int e = base + eg;
    int r = row[e], c = col[e];
    const float* cr = coord + r * 12;
    const float* cc = coord + c * 12;
    float rad = 0.f;
#pragma unroll
    for (int d = 0; d < 3; ++d) {
      float a = cr[c4 * 3 + d] - cc[c4 * 3 + d];
      float b = cr[f4 * 3 + d] - cc[f4 * 3 + d];
      rad += a * b;
    }
    acc += rad * rad;
  }
  acc += __shfl_xor(acc, 16);
  acc += __shfl_xor(acc, 32);
  if (lane < 16) atomicAdd(norm_acc + cf, acc);
}

__global__ void k_norm_fin(const float* __restrict__ norm_acc,
                           float* __restrict__ rnorm) {
  int i = threadIdx.x;
  if (i < 16) rnorm[i] = 1.0f / fmaxf(sqrtf(norm_acc[i]), 1e-12f);
}

// ---------------- CSR build ----------------
__global__ void k_count(const int* __restrict__ row, int* __restrict__ deg) {
  int e = blockIdx.x * 256 + threadIdx.x;
  if (e < NE) atomicAdd(deg + row[e], 1);
}

__global__ void k_scan(const int* __restrict__ deg, int* __restrict__ startA,
                       int* __restrict__ cursor) {
  __shared__ int part[1024];
  const int t = threadIdx.x;
  const int CH = (NN + 1023) / 1024;
  const int lo = t * CH, hi = (lo + CH < NN) ? lo + CH : NN;
  int s = 0;
  for (int i = lo; i < hi; ++i) s += deg[i];
  part[t] = s;
  __syncthreads();
  for (int off = 1; off < 1024; off <<= 1) {
    int v = (t >= off) ? part[t - off] : 0;
    __syncthreads();
    part[t] += v;
    __syncthreads();
  }
  int base = (t == 0) ? 0 : part[t - 1];
  for (int i = lo; i < hi; ++i) {
    startA[i] = base; cursor[i] = base; base += deg[i];
  }
  if (t == 1023) startA[NN] = base;
}

__global__ void k_scatter(const int* __restrict__ row, int* __restrict__ cursor,
                          int* __restrict__ eperm) {
  int e = blockIdx.x * 256 + threadIdx.x;
  if (e < NE) {
    int p = atomicAdd(cursor + row[e], 1);
    eperm[p] = e;
  }
}

// ---------------- q = h@Wq + bq (bf16 out) ----------------
__global__ __launch_bounds__(256)
void k_q(const float* __restrict__ h, const float* __restrict__ Wq,
         const float* __restrict__ bq, unsigned short* __restrict__ qg) {
  __shared__ unsigned sWqp[32 * 64];
  __shared__ float sHr[4][64];
  const int tid = threadIdx.x;
  for (int idx = tid; idx < 32 * 64; idx += 256) {
    int i2 = idx >> 6, j = idx & 63;
    sWqp[idx] = pack_bf(Wq[(2 * i2) * 64 + j], Wq[(2 * i2 + 1) * 64 + j]);
  }
  __syncthreads();
  const int wv = tid >> 6, lane = tid & 63;
  const int node = blockIdx.x * 4 + wv;
  sHr[wv][lane] = h[node * 64 + lane];
  float q = bq[lane];
  const float2* hp = (const float2*)sHr[wv];
#pragma unroll 8
  for (int i2 = 0; i2 < 32; ++i2) {
    unsigned w = sWqp[i2 * 64 + lane];
    float2 hb = hp[i2];
    q += hb.x * blo(w) + hb.y * bhi(w);
  }
  qg[node * 64 + lane] = bf16_of(q);
}

// ---------------- main MFMA GEMM over 64 CSR slots per block ----------------
__global__ __launch_bounds__(256, 2)
void k_kv(const float* __restrict__ h, const float* __restrict__ coord,
          const int* __restrict__ row, const int* __restrict__ col,
          const float* __restrict__ edge_attr,
          const float* __restrict__ Wkv, const float* __restrict__ bkv,
          const float* __restrict__ W1, const float* __restrict__ b1,
          const float* __restrict__ W2, const float* __restrict__ rnorm,
          const int* __restrict__ eperm, const unsigned short* __restrict__ qg,
          float* __restrict__ alpha_g, unsigned short* __restrict__ vg,
          float4* __restrict__ cv4g) {
  __shared__ __align__(16) unsigned short sA[64][104];   // feat bf16
  __shared__ __align__(16) unsigned short sB[128][104];  // [k cols | v cols]^T
  __shared__ __align__(16) unsigned short sW1t[64][80];  // W1^T
  __shared__ __align__(16) unsigned short vbuf[64][80];  // v bf16
  __shared__ unsigned short sQ[64][72];
  __shared__ int sCol[64], sRow[64], sE[64];
  __shared__ float cdb[64][12];

  const int tid = threadIdx.x;
  const int base = blockIdx.x * 64;

  if (tid < 64) {
    int e = eperm[base + tid];
    sE[tid] = e; sCol[tid] = col[e]; sRow[tid] = row[e];
  }
  for (int idx = tid; idx < 128 * 96; idx += 256) {
    int n = idx & 127, kk = idx >> 7;
    float w = (n < 64) ? Wkv[kk * 128 + 2 * n] : Wkv[kk * 128 + 2 * (n - 64) + 1];
    sB[n][kk] = bf16_of(w);
  }
  for (int idx = tid; idx < 64 * 64; idx += 256) {
    int n = idx & 63, kk = idx >> 6;
    sW1t[n][kk] = bf16_of(W1[kk * 64 + n]);
  }
  __syncthreads();  // sCol/sRow/sE ready
  for (int idx = tid; idx < 64 * 12; idx += 256) {
    int s = idx / 12, d = idx % 12;
    cdb[s][d] = coord[sRow[s] * 12 + d] - coord[sCol[s] * 12 + d];
  }
  for (int idx = tid; idx < 64 * 64; idx += 256) {
    int s = idx >> 6, c = idx & 63;
    sA[s][16 + c] = bf16_of(h[sCol[s] * 64 + c]);
    sQ[s][c] = qg[sRow[s] * 64 + c];
  }
  for (int idx = tid; idx < 64 * 16; idx += 256) {
    int s = idx >> 4, c = idx & 15;
    sA[s][80 + c] = bf16_of(edge_attr[sE[s] * 16 + c]);
  }
  __syncthreads();  // cdb ready
  for (int idx = tid; idx < 64 * 16; idx += 256) {
    int s = idx >> 4, cf = idx & 15;
    int c4 = cf >> 2, f4 = cf & 3;
    float r3 = cdb[s][c4 * 3 + 0] * cdb[s][f4 * 3 + 0] +
               cdb[s][c4 * 3 + 1] * cdb[s][f4 * 3 + 1] +
               cdb[s][c4 * 3 + 2] * cdb[s][f4 * 3 + 2];
    sA[s][cf] = bf16_of(r3 * rnorm[cf]);
  }
  __syncthreads();  // sA complete

  const int wv = tid >> 6, lane = tid & 63;
  const int m16 = lane & 15, quad = lane >> 4;
  const int arow = 16 * wv + m16;

  // K-loop: kv = feat @ [Wk|Wv]   (acc 0..3 = k cols, 4..7 = v cols)
  floatx4 acc[8];
#pragma unroll
  for (int i = 0; i < 8; ++i) acc[i] = (floatx4){0.f, 0.f, 0.f, 0.f};
#pragma unroll
  for (int ks = 0; ks < 3; ++ks) {
    short8 af = *(const short8*)&sA[arow][ks * 32 + quad * 8];
#pragma unroll
    for (int nt = 0; nt < 8; ++nt) {
      short8 bf = *(const short8*)&sB[nt * 16 + m16][ks * 32 + quad * 8];
      acc[nt] = __builtin_amdgcn_mfma_f32_16x16x32_bf16(af, bf, acc[nt], 0, 0, 0);
    }
  }
  // biases
#pragma unroll
  for (int nt = 0; nt < 4; ++nt) {
    float bk = bkv[2 * (m16 + 16 * nt)];
    float bv = bkv[2 * (m16 + 16 * nt) + 1];
#pragma unroll
    for (int r = 0; r < 4; ++r) { acc[nt][r] += bk; acc[nt + 4][r] += bv; }
  }
  // alpha = q . k   (rows quad*4+r of this wave's 16-slot tile)
  float part[4] = {0.f, 0.f, 0.f, 0.f};
#pragma unroll
  for (int nt = 0; nt < 4; ++nt) {
#pragma unroll
    for (int r = 0; r < 4; ++r) {
      float qv = bf2f(sQ[16 * wv + quad * 4 + r][m16 + 16 * nt]);
      part[r] += qv * acc[nt][r];
    }
  }
#pragma unroll
  for (int off = 1; off < 16; off <<= 1) {
#pragma unroll
    for (int r = 0; r < 4; ++r) part[r] += __shfl_xor(part[r], off);
  }
  if (m16 == 0) {
#pragma unroll
    for (int r = 0; r < 4; ++r)
      alpha_g[base + 16 * wv + quad * 4 + r] = part[r];
  }
  // v -> LDS (bf16), then linear global write
#pragma unroll
  for (int nt = 0; nt < 4; ++nt)
#pragma unroll
    for (int r = 0; r < 4; ++r)
      vbuf[16 * wv + quad * 4 + r][m16 + 16 * nt] = bf16_of(acc[4 + nt][r]);
  for (int i = lane; i < 16 * 32; i += 64) {   // 16 rows x 32 dwords
    int r = i >> 5, dw = i & 31;
    unsigned u = *(const unsigned*)&vbuf[16 * wv + r][dw * 2];
    ((unsigned*)vg)[(size_t)(base + 16 * wv + r) * 32 + dw] = u;
  }
  // t = silu(v @ W1 + b1)
  floatx4 tacc[4];
#pragma unroll
  for (int i = 0; i < 4; ++i) tacc[i] = (floatx4){0.f, 0.f, 0.f, 0.f};
#pragma unroll
  for (int ks = 0; ks < 2; ++ks) {
    short8 af = *(const short8*)&vbuf[arow][ks * 32 + quad * 8];
#pragma unroll
    for (int nt = 0; nt < 4; ++nt) {
      short8 bf = *(const short8*)&sW1t[nt * 16 + m16][ks * 32 + quad * 8];
      tacc[nt] = __builtin_amdgcn_mfma_f32_16x16x32_bf16(af, bf, tacc[nt], 0, 0, 0);
    }
  }
#pragma unroll
  for (int nt = 0; nt < 4; ++nt) {
    float bb = b1[m16 + 16 * nt];
#pragma unroll
    for (int r = 0; r < 4; ++r) {
      float t = tacc[nt][r] + bb;
      tacc[nt][r] = t / (1.f + __expf(-t));
    }
  }
  // cv = t @ W2  (64x4)
  float cvp[4][4];
#pragma unroll
  for (int r = 0; r < 4; ++r)
#pragma unroll
    for (int c = 0; c < 4; ++c) cvp[r][c] = 0.f;
#pragma unroll
  for (int nt = 0; nt < 4; ++nt) {
    float4 w2r = ((const float4*)W2)[m16 + 16 * nt];
#pragma unroll
    for (int r = 0; r < 4; ++r) {
      cvp[r][0] += tacc[nt][r] * w2r.x;
      cvp[r][1] += tacc[nt][r] * w2r.y;
      cvp[r][2] += tacc[nt][r] * w2r.z;
      cvp[r][3] += tacc[nt][r] * w2r.w;
    }
  }
#pragma unroll
  for (int off = 1; off < 16; off <<= 1) {
#pragma unroll
    for (int r = 0; r < 4; ++r)
#pragma unroll
      for (int c = 0; c < 4; ++c) cvp[r][c] += __shfl_xor(cvp[r][c], off);
  }
  if (m16 == 0) {
#pragma unroll
    for (int r = 0; r < 4; ++r)
      cv4g[base + 16 * wv + quad * 4 + r] =
          make_float4(cvp[r][0], cvp[r][1], cvp[r][2], cvp[r][3]);
  }
}

// ---------------- per-node softmax + accumulate ----------------
__global__ __launch_bounds__(256)
void k_accum(const float* __restrict__ h, const float* __restrict__ coord,
             const int* __restrict__ col, const int* __restrict__ startA,
             const int* __restrict__ eperm, const float* __restrict__ alpha_g,
             const unsigned short* __restrict__ vg, const float4* __restrict__ cv4g,
             float* __restrict__ out) {
  const int wv = threadIdx.x >> 6, lane = threadIdx.x & 63;
  const int node = blockIdx.x * 4 + wv;
  const int s0 = startA[node], s1 = startA[node + 1];

  // pass 1: max
  float mx = -INFINITY;
  for (int j = s0 + lane; j < s1; j += 64) mx = fmaxf(mx, alpha_g[j]);
#pragma unroll
  for (int off = 1; off < 64; off <<= 1) mx = fmaxf(mx, __shfl_xor(mx, off));

  const float cdr = (lane < 12) ? coord[node * 12 + lane] : 0.f;
  const int ci = (lane < 12) ? (lane / 3) : 0;

  float l = 0.f, hacc = 0.f, cacc = 0.f;
  for (int j = s0; j < s1; ++j) {
    float a = alpha_g[j];
    float ex = __expf(a - mx);
    l += ex;
    hacc += ex * bf2f(vg[(size_t)j * 64 + lane]);
    float4 cv = cv4g[j];
    float cvc = (ci == 0) ? cv.x : (ci == 1) ? cv.y : (ci == 2) ? cv.z : cv.w;
    int e = eperm[j];
    int cn = col[e];
    float cd = (lane < 12) ? (cdr - coord[cn * 12 + lane]) : 0.f;
    cacc += ex * cvc * cd;
  }
  const float inv = (l > 0.f) ? 1.f / l : 0.f;
  out[node * 64 + lane] = h[node * 64 + lane] + hacc * inv;
  if (lane < 12)
    out[NN * 64 + node * 12 + lane] = cdr + cacc * inv;
  for (int j = s0 + lane; j < s1; j += 64)
    out[NN * 64 + NN * 12 + eperm[j]] = __expf(alpha_g[j] - mx) * inv;
}

extern "C" void kernel_launch(void* const* d_in, const int* in_sizes, int n_in,
                              void* d_out, int out_size, void* d_ws, size_t ws_size,
                              hipStream_t stream) {
  const float* h         = (const float*)d_in[0];
  const float* coord     = (const float*)d_in[1];
  const int*   row       = (const int*)d_in[2];
  const int*   col       = (const int*)d_in[3];
  const float* edge_attr = (const float*)d_in[4];
  const float* Wq        = (const float*)d_in[5];
  const float* bq        = (const float*)d_in[6];
  const float* Wkv       = (const float*)d_in[7];
  const float* bkv       = (const float*)d_in[8];
  const float* W1        = (const float*)d_in[9];
  const float* b1        = (const float*)d_in[10];
  const float* W2        = (const float*)d_in[11];
  float* out = (float*)d_out;

  // workspace carve-up (256B aligned chunks)
  size_t off = 0;
  char* wsb = (char*)d_ws;
  auto alloc = [&](size_t bytes) {
    off = (off + 255) & ~(size_t)255;
    void* p = wsb + off; off += bytes; return p;
  };
  float*          norm_acc = (float*)alloc(16 * 4);
  float*          rnorm    = (float*)alloc(16 * 4);
  int*            deg      = (int*)alloc((size_t)NN * 4);
  int*            startA   = (int*)alloc(((size_t)NN + 1) * 4);
  int*            cursor   = (int*)alloc((size_t)NN * 4);
  int*            eperm    = (int*)alloc((size_t)NE * 4);
  float*          alpha_g  = (float*)alloc((size_t)NE * 4);
  unsigned short* qg       = (unsigned short*)alloc((size_t)NN * 64 * 2);
  float4*         cv4g     = (float4*)alloc((size_t)NE * 16);
  unsigned short* vg       = (unsigned short*)alloc((size_t)NE * 64 * 2);

  hipMemsetAsync(norm_acc, 0, 16 * 4, stream);
  hipMemsetAsync(deg, 0, (size_t)NN * 4, stream);

  k_radnorm<<<1024, 256, 0, stream>>>(coord, row, col, norm_acc);
  k_norm_fin<<<1, 64, 0, stream>>>(norm_acc, rnorm);
  k_count<<<(NE + 255) / 256, 256, 0, stream>>>(row, deg);
  k_scan<<<1, 1024, 0, stream>>>(deg, startA, cursor);
  k_scatter<<<(NE + 255) / 256, 256, 0, stream>>>(row, cursor, eperm);
  k_q<<<NN / 4, 256, 0, stream>>>(h, Wq, bq, qg);
  k_kv<<<NE / 64, 256, 0, stream>>>(h, coord, row, col, edge_attr, Wkv, bkv,
                                    W1, b1, W2, rnorm, eperm, qg,
                                    alpha_g, vg, cv4g);
  k_accum<<<NN / 4, 256, 0, stream>>>(h, coord, col, startA, eperm, alpha_g,
                                      vg, cv4g, out);
}

// Round 4
// 686.527 us; speedup vs baseline: 4.0076x; 1.3775x over previous
//
#include <hip/hip_runtime.h>
#include <math.h>

#define NN 50000
#define NE 800000

typedef __attribute__((ext_vector_type(8))) short short8;
typedef __attribute__((ext_vector_type(4))) float floatx4;

__device__ __forceinline__ unsigned short bf16_of(float x) {
  unsigned u = __float_as_uint(x);
  u += 0x7fffu + ((u >> 16) & 1u);
  return (unsigned short)(u >> 16);
}
__device__ __forceinline__ float bf2f(unsigned short u) {
  return __uint_as_float(((unsigned)u) << 16);
}
__device__ __forceinline__ unsigned pack_bf(float a, float b) {
  unsigned ua = __float_as_uint(a); ua += 0x7fffu + ((ua >> 16) & 1u);
  unsigned ub = __float_as_uint(b); ub += 0x7fffu + ((ub >> 16) & 1u);
  return (ua >> 16) | (ub & 0xffff0000u);
}
__device__ __forceinline__ float blo(unsigned w) { return __uint_as_float(w << 16); }
__device__ __forceinline__ float bhi(unsigned w) { return __uint_as_float(w & 0xffff0000u); }

// ---------------- norm over all edges + degree count ----------------
__global__ __launch_bounds__(256)
void k_radnorm(const float* __restrict__ coord, const int* __restrict__ row,
               const int* __restrict__ col, float* __restrict__ norm_acc,
               int* __restrict__ deg) {
  const int lane = threadIdx.x & 63;
  const int cf = lane & 15;
  const int eg = lane >> 4;
  const int c4 = cf >> 2, f4 = cf & 3;
  const int wid = blockIdx.x * (blockDim.x >> 6) + (threadIdx.x >> 6);
  const int nw = gridDim.x * (blockDim.x >> 6);
  float acc = 0.f;
  for (int base = wid * 4; base < NE; base += nw * 4) {
    int e = base + eg;
    int r = row[e], c = col[e];
    const float* cr = coord + r * 12;
    const float* cc = coord + c * 12;
    float rad = 0.f;
#pragma unroll
    for (int d = 0; d < 3; ++d) {
      float a = cr[c4 * 3 + d] - cc[c4 * 3 + d];
      float b = cr[f4 * 3 + d] - cc[f4 * 3 + d];
      rad += a * b;
    }
    acc += rad * rad;
    if (cf == 0) atomicAdd(deg + r, 1);
  }
  acc += __shfl_xor(acc, 16);
  acc += __shfl_xor(acc, 32);
  if (lane < 16) atomicAdd(norm_acc + cf, acc);
}

__global__ void k_norm_fin(const float* __restrict__ norm_acc,
                           float* __restrict__ rnorm) {
  int i = threadIdx.x;
  if (i < 16) rnorm[i] = 1.0f / fmaxf(sqrtf(norm_acc[i]), 1e-12f);
}

// ---------------- weight pre-conversion (once) ----------------
// Bkvb [128][104]: rows 0..63 = k cols, 64..127 = v cols; [n][kk]=W^T bf16
// W1tb [64][88]:  [n][kk] = W1[kk][n] bf16
// Wqp  [32][64]:  packed bf16 pairs of Wq (k-major pairs)
__global__ __launch_bounds__(256)
void k_prep(const float* __restrict__ Wkv, const float* __restrict__ W1,
            const float* __restrict__ Wq, unsigned short* __restrict__ Bkvb,
            unsigned short* __restrict__ W1tb, unsigned* __restrict__ Wqp) {
  const int gid = blockIdx.x * 256 + threadIdx.x;
  const int np = gridDim.x * 256;
  for (int idx = gid; idx < 128 * 96; idx += np) {
    int n = idx & 127, kk = idx >> 7;
    float w = (n < 64) ? Wkv[kk * 128 + 2 * n] : Wkv[kk * 128 + 2 * (n - 64) + 1];
    Bkvb[n * 104 + kk] = bf16_of(w);
  }
  for (int idx = gid; idx < 64 * 64; idx += np) {
    int n = idx & 63, kk = idx >> 6;
    W1tb[n * 88 + kk] = bf16_of(W1[kk * 64 + n]);
  }
  for (int idx = gid; idx < 32 * 64; idx += np) {
    int i2 = idx >> 6, j = idx & 63;
    Wqp[idx] = pack_bf(Wq[(2 * i2) * 64 + j], Wq[(2 * i2 + 1) * 64 + j]);
  }
}

// ---------------- CSR scan + scatter ----------------
__global__ void k_scan(const int* __restrict__ deg, int* __restrict__ startA,
                       int* __restrict__ cursor) {
  __shared__ int part[1024];
  const int t = threadIdx.x;
  const int CH = (NN + 1023) / 1024;
  const int lo = t * CH, hi = (lo + CH < NN) ? lo + CH : NN;
  int s = 0;
  for (int i = lo; i < hi; ++i) s += deg[i];
  part[t] = s;
  __syncthreads();
  for (int off = 1; off < 1024; off <<= 1) {
    int v = (t >= off) ? part[t - off] : 0;
    __syncthreads();
    part[t] += v;
    __syncthreads();
  }
  int base = (t == 0) ? 0 : part[t - 1];
  for (int i = lo; i < hi; ++i) {
    startA[i] = base; cursor[i] = base; base += deg[i];
  }
  if (t == 1023) startA[NN] = base;
}

__global__ void k_scatter(const int* __restrict__ row, int* __restrict__ cursor,
                          int* __restrict__ eperm) {
  int e = blockIdx.x * 256 + threadIdx.x;
  if (e < NE) {
    int p = atomicAdd(cursor + row[e], 1);
    eperm[p] = e;
  }
}

// ---------------- q = h@Wq + bq (bf16 out) ----------------
__global__ __launch_bounds__(256)
void k_q(const float* __restrict__ h, const unsigned* __restrict__ Wqp,
         const float* __restrict__ bq, unsigned short* __restrict__ qg) {
  __shared__ unsigned sWqp[32 * 64];
  __shared__ float sHr[4][64];
  const int tid = threadIdx.x;
  for (int idx = tid; idx < 2048; idx += 256) sWqp[idx] = Wqp[idx];
  __syncthreads();
  const int wv = tid >> 6, lane = tid & 63;
  const int node = blockIdx.x * 4 + wv;
  sHr[wv][lane] = h[node * 64 + lane];
  float q = bq[lane];
  const float2* hp = (const float2*)sHr[wv];
#pragma unroll 8
  for (int i2 = 0; i2 < 32; ++i2) {
    unsigned w = sWqp[i2 * 64 + lane];
    float2 hb = hp[i2];
    q += hb.x * blo(w) + hb.y * bhi(w);
  }
  qg[node * 64 + lane] = bf16_of(q);
}

// ---------------- main MFMA GEMM over 64 CSR slots per block ----------------
__global__ __launch_bounds__(256, 3)
void k_kv(const float* __restrict__ h, const float* __restrict__ coord,
          const int* __restrict__ row, const int* __restrict__ col,
          const float* __restrict__ edge_attr, const float* __restrict__ bkv,
          const float* __restrict__ b1, const float* __restrict__ W2,
          const float* __restrict__ rnorm, const int* __restrict__ eperm,
          const unsigned short* __restrict__ Bkvb,
          const unsigned short* __restrict__ W1tb,
          const unsigned short* __restrict__ qg,
          float* __restrict__ alpha_g, unsigned short* __restrict__ vg,
          unsigned short* __restrict__ transg) {
  __shared__ __align__(16) unsigned short sA[64][104];   // feat bf16; later v
  __shared__ __align__(16) unsigned short sB[128][104];  // [k|v]^T bf16
  __shared__ __align__(16) unsigned short sW1t[64][88];  // W1^T bf16
  __shared__ unsigned short cdb[64][12];                 // coord_diff bf16
  __shared__ int sCol[64], sRow[64], sE[64];

  const int tid = threadIdx.x;
  const int base = blockIdx.x * 64;

  if (tid < 64) {
    int e = eperm[base + tid];
    sE[tid] = e; sCol[tid] = col[e]; sRow[tid] = row[e];
  }
  // weights: pure vector copies (L2-hot, zero conversion)
  {
    const uint4* gb = (const uint4*)Bkvb;
    uint4* sb = (uint4*)&sB[0][0];
    for (int idx = tid; idx < 1664; idx += 256) sb[idx] = gb[idx];
    const uint4* gw = (const uint4*)W1tb;
    uint4* sw = (uint4*)&sW1t[0][0];
    for (int idx = tid; idx < 704; idx += 256) sw[idx] = gw[idx];
  }
  __syncthreads();   // sCol/sRow/sE visible

  // h[col] gather: 64 rows x 32 dword-cols (pairwise pack)
  for (int idx = tid; idx < 2048; idx += 256) {
    int s = idx >> 5, c2 = idx & 31;
    float2 hb = ((const float2*)(h + (size_t)sCol[s] * 64))[c2];
    *(unsigned*)&sA[s][16 + 2 * c2] = pack_bf(hb.x, hb.y);
  }
  // edge_attr: 64 rows x 8 dword-cols
  for (int idx = tid; idx < 512; idx += 256) {
    int s = idx >> 3, c2 = idx & 7;
    float2 ea = ((const float2*)(edge_attr + (size_t)sE[s] * 16))[c2];
    *(unsigned*)&sA[s][80 + 2 * c2] = pack_bf(ea.x, ea.y);
  }
  // radial + cdb via register shuffles: wave wv stages slots [16wv,16wv+16)
  {
    const int wv = tid >> 6, lane = tid & 63;
    const int grp = lane >> 4, g = lane & 15;
    const int c4 = g >> 2, f4 = g & 3;
    const float rn = rnorm[g];
#pragma unroll
    for (int it = 0; it < 4; ++it) {
      int slot = 16 * wv + it * 4 + grp;
      int r = sRow[slot], c = sCol[slot];
      float cd = 0.f;
      if (g < 12) cd = coord[r * 12 + g] - coord[c * 12 + g];
      float rad = 0.f;
#pragma unroll
      for (int d = 0; d < 3; ++d)
        rad += __shfl(cd, grp * 16 + c4 * 3 + d) * __shfl(cd, grp * 16 + f4 * 3 + d);
      sA[slot][g] = bf16_of(rad * rn);
      if (g < 12) cdb[slot][g] = bf16_of(cd);
    }
  }
  __syncthreads();   // sA complete

  const int wv = tid >> 6, lane = tid & 63;
  const int m16 = lane & 15, quad = lane >> 4;
  const int arow = 16 * wv + m16;

  // kv = feat @ [Wk|Wv]
  floatx4 acc[8];
#pragma unroll
  for (int i = 0; i < 8; ++i) acc[i] = (floatx4){0.f, 0.f, 0.f, 0.f};
#pragma unroll
  for (int ks = 0; ks < 3; ++ks) {
    short8 af = *(const short8*)&sA[arow][ks * 32 + quad * 8];
#pragma unroll
    for (int nt = 0; nt < 8; ++nt) {
      short8 bf = *(const short8*)&sB[nt * 16 + m16][ks * 32 + quad * 8];
      acc[nt] = __builtin_amdgcn_mfma_f32_16x16x32_bf16(af, bf, acc[nt], 0, 0, 0);
    }
  }
#pragma unroll
  for (int nt = 0; nt < 4; ++nt) {
    float bk = bkv[2 * (m16 + 16 * nt)];
    float bv = bkv[2 * (m16 + 16 * nt) + 1];
#pragma unroll
    for (int r = 0; r < 4; ++r) { acc[nt][r] += bk; acc[nt + 4][r] += bv; }
  }
  // alpha = q . k  (q rows straight from L2)
  float part[4] = {0.f, 0.f, 0.f, 0.f};
#pragma unroll
  for (int nt = 0; nt < 4; ++nt) {
#pragma unroll
    for (int r = 0; r < 4; ++r) {
      float qv = bf2f(qg[(size_t)sRow[16 * wv + quad * 4 + r] * 64 + m16 + 16 * nt]);
      part[r] += qv * acc[nt][r];
    }
  }
#pragma unroll
  for (int off = 1; off < 16; off <<= 1) {
#pragma unroll
    for (int r = 0; r < 4; ++r) part[r] += __shfl_xor(part[r], off);
  }
  if (m16 == 0) {
#pragma unroll
    for (int r = 0; r < 4; ++r)
      alpha_g[base + 16 * wv + quad * 4 + r] = part[r];
  }
  // v -> sA rows (wave-private), then linear global write
#pragma unroll
  for (int nt = 0; nt < 4; ++nt)
#pragma unroll
    for (int r = 0; r < 4; ++r)
      sA[16 * wv + quad * 4 + r][m16 + 16 * nt] = bf16_of(acc[4 + nt][r]);
  for (int i = lane; i < 16 * 32; i += 64) {
    int r = i >> 5, dw = i & 31;
    unsigned u = *(const unsigned*)&sA[16 * wv + r][dw * 2];
    ((unsigned*)vg)[(size_t)(base + 16 * wv + r) * 32 + dw] = u;
  }
  // t = silu(v @ W1 + b1)
  floatx4 tacc[4];
#pragma unroll
  for (int i = 0; i < 4; ++i) tacc[i] = (floatx4){0.f, 0.f, 0.f, 0.f};
#pragma unroll
  for (int ks = 0; ks < 2; ++ks) {
    short8 af = *(const short8*)&sA[arow][ks * 32 + quad * 8];
#pragma unroll
    for (int nt = 0; nt < 4; ++nt) {
      short8 bf = *(const short8*)&sW1t[nt * 16 + m16][ks * 32 + quad * 8];
      tacc[nt] = __builtin_amdgcn_mfma_f32_16x16x32_bf16(af, bf, tacc[nt], 0, 0, 0);
    }
  }
#pragma unroll
  for (int nt = 0; nt < 4; ++nt) {
    float bb = b1[m16 + 16 * nt];
#pragma unroll
    for (int r = 0; r < 4; ++r) {
      float t = tacc[nt][r] + bb;
      tacc[nt][r] = t / (1.f + __expf(-t));
    }
  }
  // cv = t @ W2 (all-reduce across the 16-lane group)
  float cvp[4][4];
#pragma unroll
  for (int r = 0; r < 4; ++r)
#pragma unroll
    for (int c = 0; c < 4; ++c) cvp[r][c] = 0.f;
#pragma unroll
  for (int nt = 0; nt < 4; ++nt) {
    float4 w2r = ((const float4*)W2)[m16 + 16 * nt];
#pragma unroll
    for (int r = 0; r < 4; ++r) {
      cvp[r][0] += tacc[nt][r] * w2r.x;
      cvp[r][1] += tacc[nt][r] * w2r.y;
      cvp[r][2] += tacc[nt][r] * w2r.z;
      cvp[r][3] += tacc[nt][r] * w2r.w;
    }
  }
#pragma unroll
  for (int off = 1; off < 16; off <<= 1) {
#pragma unroll
    for (int r = 0; r < 4; ++r)
#pragma unroll
      for (int c = 0; c < 4; ++c) cvp[r][c] += __shfl_xor(cvp[r][c], off);
  }
  // trans = cd * cv  (bf16)  — kills k_accum's random coord gather
#pragma unroll
  for (int r = 0; r < 4; ++r) {
    int row16 = quad * 4 + r;
    if (m16 < 12) {
      float cvv = (m16 < 3) ? cvp[r][0] : (m16 < 6) ? cvp[r][1]
                : (m16 < 9) ? cvp[r][2] : cvp[r][3];
      float cdv = bf2f(cdb[16 * wv + row16][m16]);
      transg[(size_t)(base + 16 * wv + row16) * 12 + m16] = bf16_of(cdv * cvv);
    }
  }
}

// ---------------- per-node softmax + accumulate (pure streaming) ----------------
__global__ __launch_bounds__(256)
void k_accum(const float* __restrict__ h, const float* __restrict__ coord,
             const int* __restrict__ startA, const int* __restrict__ eperm,
             const float* __restrict__ alpha_g,
             const unsigned short* __restrict__ vg,
             const unsigned short* __restrict__ transg,
             float* __restrict__ out) {
  const int wv = threadIdx.x >> 6, lane = threadIdx.x & 63;
  const int node = blockIdx.x * 4 + wv;
  const int s0 = startA[node], s1 = startA[node + 1];

  float mx = -INFINITY;
  for (int j = s0 + lane; j < s1; j += 64) mx = fmaxf(mx, alpha_g[j]);
#pragma unroll
  for (int off = 1; off < 64; off <<= 1) mx = fmaxf(mx, __shfl_xor(mx, off));

  float l = 0.f, h0 = 0.f, h1 = 0.f, c0 = 0.f, c1 = 0.f;
  int j = s0;
  for (; j + 1 < s1; j += 2) {
    float a0 = alpha_g[j], a1 = alpha_g[j + 1];
    float va = bf2f(vg[(size_t)j * 64 + lane]);
    float vb = bf2f(vg[(size_t)(j + 1) * 64 + lane]);
    float ta = (lane < 12) ? bf2f(transg[(size_t)j * 12 + lane]) : 0.f;
    float tb = (lane < 12) ? bf2f(transg[(size_t)(j + 1) * 12 + lane]) : 0.f;
    float e0 = __expf(a0 - mx), e1 = __expf(a1 - mx);
    l += e0 + e1;
    h0 += e0 * va; h1 += e1 * vb;
    c0 += e0 * ta; c1 += e1 * tb;
  }
  if (j < s1) {
    float a0 = alpha_g[j];
    float va = bf2f(vg[(size_t)j * 64 + lane]);
    float ta = (lane < 12) ? bf2f(transg[(size_t)j * 12 + lane]) : 0.f;
    float e0 = __expf(a0 - mx);
    l += e0; h0 += e0 * va; c0 += e0 * ta;
  }
  float hacc = h0 + h1, cacc = c0 + c1;
  const float inv = (l > 0.f) ? 1.f / l : 0.f;
  out[node * 64 + lane] = h[node * 64 + lane] + hacc * inv;
  if (lane < 12)
    out[NN * 64 + node * 12 + lane] = coord[node * 12 + lane] + cacc * inv;
  for (int j2 = s0 + lane; j2 < s1; j2 += 64)
    out[NN * 64 + NN * 12 + eperm[j2]] = __expf(alpha_g[j2] - mx) * inv;
}

extern "C" void kernel_launch(void* const* d_in, const int* in_sizes, int n_in,
                              void* d_out, int out_size, void* d_ws, size_t ws_size,
                              hipStream_t stream) {
  const float* h         = (const float*)d_in[0];
  const float* coord     = (const float*)d_in[1];
  const int*   row       = (const int*)d_in[2];
  const int*   col       = (const int*)d_in[3];
  const float* edge_attr = (const float*)d_in[4];
  const float* Wq        = (const float*)d_in[5];
  const float* bq        = (const float*)d_in[6];
  const float* Wkv       = (const float*)d_in[7];
  const float* bkv       = (const float*)d_in[8];
  const float* W1        = (const float*)d_in[9];
  const float* b1        = (const float*)d_in[10];
  const float* W2        = (const float*)d_in[11];
  float* out = (float*)d_out;

  size_t off = 0;
  char* wsb = (char*)d_ws;
  auto alloc = [&](size_t bytes) {
    off = (off + 255) & ~(size_t)255;
    void* p = wsb + off; off += bytes; return p;
  };
  float*          norm_acc = (float*)alloc(16 * 4);
  float*          rnorm    = (float*)alloc(16 * 4);
  int*            deg      = (int*)alloc((size_t)NN * 4);
  int*            startA   = (int*)alloc(((size_t)NN + 1) * 4);
  int*            cursor   = (int*)alloc((size_t)NN * 4);
  int*            eperm    = (int*)alloc((size_t)NE * 4);
  float*          alpha_g  = (float*)alloc((size_t)NE * 4);
  unsigned short* qg       = (unsigned short*)alloc((size_t)NN * 64 * 2);
  unsigned short* Bkvb     = (unsigned short*)alloc(128 * 104 * 2);
  unsigned short* W1tb     = (unsigned short*)alloc(64 * 88 * 2);
  unsigned*       Wqp      = (unsigned*)alloc(32 * 64 * 4);
  unsigned short* transg   = (unsigned short*)alloc((size_t)NE * 12 * 2);
  unsigned short* vg       = (unsigned short*)alloc((size_t)NE * 64 * 2);

  hipMemsetAsync(norm_acc, 0, 16 * 4, stream);
  hipMemsetAsync(deg, 0, (size_t)NN * 4, stream);

  k_radnorm<<<1024, 256, 0, stream>>>(coord, row, col, norm_acc, deg);
  k_norm_fin<<<1, 64, 0, stream>>>(norm_acc, rnorm);
  k_prep<<<32, 256, 0, stream>>>(Wkv, W1, Wq, Bkvb, W1tb, Wqp);
  k_scan<<<1, 1024, 0, stream>>>(deg, startA, cursor);
  k_scatter<<<(NE + 255) / 256, 256, 0, stream>>>(row, cursor, eperm);
  k_q<<<NN / 4, 256, 0, stream>>>(h, Wqp, bq, qg);
  k_kv<<<NE / 64, 256, 0, stream>>>(h, coord, row, col, edge_attr, bkv, b1, W2,
                                    rnorm, eperm, Bkvb, W1tb, qg,
                                    alpha_g, vg, transg);
  k_accum<<<NN / 4, 256, 0, stream>>>(h, coord, startA, eperm, alpha_g, vg,
                                      transg, out);
}